// Round 12
// baseline (428.042 us; speedup 1.0000x reference)
//
#include <hip/hip_runtime.h>
#include <cstdint>
#include <cmath>

#define E_DIM 1024
#define FF_DIM 4096
#define B_DIM 4
#define S_DIM 2048
#define NTOK (B_DIM * S_DIM)  // 8192
#define QKV_N 3072

typedef __bf16 bf16;
typedef __attribute__((ext_vector_type(8))) __bf16 bf16x8;
typedef __attribute__((ext_vector_type(4))) float f32x4;

// ---- async global->LDS, 16B per lane (HW: dest = wave-uniform base + lane*16)
__device__ __forceinline__ void gload_lds16(const void* g, void* l) {
  __builtin_amdgcn_global_load_lds(
      (const __attribute__((address_space(1))) unsigned int*)g,
      (__attribute__((address_space(3))) unsigned int*)l, 16, 0, 0);
}

__device__ __forceinline__ float waveRedSum(float v) {
#pragma unroll
  for (int o = 32; o > 0; o >>= 1) v += __shfl_xor(v, o, 64);
  return v;
}
__device__ __forceinline__ float waveRedMax(float v) {
#pragma unroll
  for (int o = 32; o > 0; o >>= 1) v = fmaxf(v, __shfl_xor(v, o, 64));
  return v;
}

// ---------------- fp32 -> bf16 convert (weights), 4 elems/thread -------------
__global__ __launch_bounds__(256) void cvt_k(const float* __restrict__ in,
                                             bf16* __restrict__ out, int n4) {
  int i = blockIdx.x * 256 + threadIdx.x;
  if (i < n4) {
    float4 v = reinterpret_cast<const float4*>(in)[i];
    bf16* o = out + (size_t)i * 4;
    o[0] = (bf16)v.x; o[1] = (bf16)v.y; o[2] = (bf16)v.z; o[3] = (bf16)v.w;
  }
}

// ---------------- LayerNorm over E=1024, one block (256 thr) per row ---------
template <typename OutT>
__global__ __launch_bounds__(256) void layernorm_k(const float* __restrict__ x,
                                                   OutT* __restrict__ out,
                                                   const float* __restrict__ g,
                                                   const float* __restrict__ b) {
  const int row = blockIdx.x;
  const int tid = threadIdx.x;
  const float4 v = reinterpret_cast<const float4*>(x + (size_t)row * E_DIM)[tid];
  float s = v.x + v.y + v.z + v.w;
  float q = v.x * v.x + v.y * v.y + v.z * v.z + v.w * v.w;
  s = waveRedSum(s);
  q = waveRedSum(q);
  __shared__ float sa[4], sb[4];
  const int lane = tid & 63, wid = tid >> 6;
  if (lane == 0) { sa[wid] = s; sb[wid] = q; }
  __syncthreads();
  s = sa[0] + sa[1] + sa[2] + sa[3];
  q = sb[0] + sb[1] + sb[2] + sb[3];
  const float mean = s * (1.0f / E_DIM);
  const float var = q * (1.0f / E_DIM) - mean * mean;
  const float rstd = rsqrtf(var + 1e-5f);
  const int c = tid * 4;
  OutT* op = out + (size_t)row * E_DIM + c;
  const float vv[4] = {v.x, v.y, v.z, v.w};
#pragma unroll
  for (int j = 0; j < 4; ++j)
    op[j] = (OutT)((vv[j] - mean) * rstd * g[c + j] + b[c + j]);
}

// ---- LN2 fused with Wo split-K reduce: x = src + p0 + p1 + bo;
// h(d_out,fp32) = x;  hn(bf16) = LN(x, g2, b2) --------------------------------
__global__ __launch_bounds__(256) void ln2_fused_k(
    const float* __restrict__ src, const bf16* __restrict__ p0,
    const bf16* __restrict__ p1, const float* __restrict__ bo,
    float* __restrict__ h, bf16* __restrict__ hn,
    const float* __restrict__ g, const float* __restrict__ b) {
  const int row = blockIdx.x;
  const int tid = threadIdx.x;
  const int c = tid * 4;
  const float4 sv = reinterpret_cast<const float4*>(src + (size_t)row * E_DIM)[tid];
  const ushort4 a0 = reinterpret_cast<const ushort4*>(p0 + (size_t)row * E_DIM)[tid];
  const ushort4 a1 = reinterpret_cast<const ushort4*>(p1 + (size_t)row * E_DIM)[tid];
  const float4 bv = reinterpret_cast<const float4*>(bo)[tid];
  auto b2f = [](unsigned short u) {
    union { unsigned int i; float f; } t; t.i = (unsigned int)u << 16; return t.f;
  };
  float x[4];
  x[0] = sv.x + b2f(a0.x) + b2f(a1.x) + bv.x;
  x[1] = sv.y + b2f(a0.y) + b2f(a1.y) + bv.y;
  x[2] = sv.z + b2f(a0.z) + b2f(a1.z) + bv.z;
  x[3] = sv.w + b2f(a0.w) + b2f(a1.w) + bv.w;
  float4 hv = {x[0], x[1], x[2], x[3]};
  reinterpret_cast<float4*>(h + (size_t)row * E_DIM)[tid] = hv;
  float s = x[0] + x[1] + x[2] + x[3];
  float q = x[0] * x[0] + x[1] * x[1] + x[2] * x[2] + x[3] * x[3];
  s = waveRedSum(s);
  q = waveRedSum(q);
  __shared__ float sa[4], sb[4];
  const int lane = tid & 63, wid = tid >> 6;
  if (lane == 0) { sa[wid] = s; sb[wid] = q; }
  __syncthreads();
  s = sa[0] + sa[1] + sa[2] + sa[3];
  q = sb[0] + sb[1] + sb[2] + sb[3];
  const float mean = s * (1.0f / E_DIM);
  const float var = q * (1.0f / E_DIM) - mean * mean;
  const float rstd = rsqrtf(var + 1e-5f);
  bf16* op = hn + (size_t)row * E_DIM + c;
#pragma unroll
  for (int j = 0; j < 4; ++j)
    op[j] = (bf16)((x[j] - mean) * rstd * g[c + j] + b[c + j]);
}

// ---- LN3 fused with FF2 split-K reduce: x = h + p0 + p1 + bias2; LN -> out --
__global__ __launch_bounds__(256) void ln3_fused_k(
    const float* __restrict__ h, const bf16* __restrict__ p0,
    const bf16* __restrict__ p1, const float* __restrict__ bias2,
    float* __restrict__ out, const float* __restrict__ g,
    const float* __restrict__ b) {
  const int row = blockIdx.x;
  const int tid = threadIdx.x;
  const int c = tid * 4;
  const float4 hv = reinterpret_cast<const float4*>(h + (size_t)row * E_DIM)[tid];
  const ushort4 a0 = reinterpret_cast<const ushort4*>(p0 + (size_t)row * E_DIM)[tid];
  const ushort4 a1 = reinterpret_cast<const ushort4*>(p1 + (size_t)row * E_DIM)[tid];
  const float4 bv = reinterpret_cast<const float4*>(bias2)[tid];
  auto b2f = [](unsigned short u) {
    union { unsigned int i; float f; } t; t.i = (unsigned int)u << 16; return t.f;
  };
  float x[4];
  x[0] = hv.x + b2f(a0.x) + b2f(a1.x) + bv.x;
  x[1] = hv.y + b2f(a0.y) + b2f(a1.y) + bv.y;
  x[2] = hv.z + b2f(a0.z) + b2f(a1.z) + bv.z;
  x[3] = hv.w + b2f(a0.w) + b2f(a1.w) + bv.w;
  float s = x[0] + x[1] + x[2] + x[3];
  float q = x[0] * x[0] + x[1] * x[1] + x[2] * x[2] + x[3] * x[3];
  s = waveRedSum(s);
  q = waveRedSum(q);
  __shared__ float sa[4], sb[4];
  const int lane = tid & 63, wid = tid >> 6;
  if (lane == 0) { sa[wid] = s; sb[wid] = q; }
  __syncthreads();
  s = sa[0] + sa[1] + sa[2] + sa[3];
  q = sb[0] + sb[1] + sb[2] + sb[3];
  const float mean = s * (1.0f / E_DIM);
  const float var = q * (1.0f / E_DIM) - mean * mean;
  const float rstd = rsqrtf(var + 1e-5f);
  float* op = out + (size_t)row * E_DIM + c;
#pragma unroll
  for (int j = 0; j < 4; ++j)
    op[j] = (x[j] - mean) * rstd * g[c + j] + b[c + j];
}

// ---------------- row softmax over S=2048, in-place bf16 ---------------------
__global__ __launch_bounds__(256) void softmax_k(bf16* __restrict__ scores) {
  const int row = blockIdx.x;
  bf16* rp = scores + (size_t)row * S_DIM;
  const int tid = threadIdx.x;
  const int lane = tid & 63, wid = tid >> 6;
  bf16x8 v8 = *reinterpret_cast<const bf16x8*>(rp + tid * 8);
  float v[8];
#pragma unroll
  for (int j = 0; j < 8; ++j) v[j] = (float)v8[j];
  float mx = v[0];
#pragma unroll
  for (int j = 1; j < 8; ++j) mx = fmaxf(mx, v[j]);
  mx = waveRedMax(mx);
  __shared__ float sm_[4], ss_[4];
  if (lane == 0) sm_[wid] = mx;
  __syncthreads();
  mx = fmaxf(fmaxf(sm_[0], sm_[1]), fmaxf(sm_[2], sm_[3]));
  float e[8];
  float s = 0.f;
#pragma unroll
  for (int j = 0; j < 8; ++j) { e[j] = __expf(v[j] - mx); s += e[j]; }
  s = waveRedSum(s);
  if (lane == 0) ss_[wid] = s;
  __syncthreads();
  s = ss_[0] + ss_[1] + ss_[2] + ss_[3];
  const float inv = 1.0f / s;
  bf16x8 o;
#pragma unroll
  for (int j = 0; j < 8; ++j) o[j] = (bf16)(e[j] * inv);
  *reinterpret_cast<bf16x8*>(rp + tid * 8) = o;
}

// -------- bf16 transpose [S][ld_in] cols -> [E][S] per batch (strided in) ----
__global__ __launch_bounds__(256) void transpose_k(const bf16* __restrict__ in,
                                                   int ld_in, size_t bstride_in,
                                                   bf16* __restrict__ out) {
  __shared__ bf16 t[32][33];
  const int b = blockIdx.z;
  const bf16* ip = in + (size_t)b * bstride_in;
  bf16* op = out + (size_t)b * S_DIM * E_DIM;
  const int e0 = blockIdx.x * 32, s0 = blockIdx.y * 32;
  const int tx = threadIdx.x & 31, ty = threadIdx.x >> 5;  // 32 x 8
#pragma unroll
  for (int r = 0; r < 32; r += 8)
    t[ty + r][tx] = ip[(size_t)(s0 + ty + r) * ld_in + e0 + tx];
  __syncthreads();
#pragma unroll
  for (int r = 0; r < 32; r += 8)
    op[(size_t)(e0 + ty + r) * S_DIM + s0 + tx] = t[tx][ty + r];
}

// ============================================================================
// 256xBN 8-wave GEMM, BK=64.
// BN=256 (r12): ROLLING REG-STAGED pipeline. Per phase: load 2 chunks of tile
//   t+1 into one of two 2xint4 reg groups (alternating parity, static idx),
//   ds_write the group loaded one phase earlier. Bypasses the slow
//   global_load_lds return path (~10 B/cy/CU measured r5-r11) via the vector
//   load path, holding only 16 staging VGPRs (r10's 48-reg burst spilled).
//   Chunk order: p0 loads B0,B1; p1 B2,B3; p2 A0,A2; p3 A1,A3. Writes: p1
//   B0,B1; p2 B2,B3; p3 A0,A2 (into buf t+1); next-tile p0 writes A1,A3
//   (late, into cur buf; first read of A1/A3 is at p2 -> >=1 barrier apart).
//   Buffer-reuse WAR separated by >=2 barriers. LDS 128 KB, wave=128x64.
// BN=128 (r11 proven): gload_lds 3-deep, 2 phases/tile, ONE vmcnt(6)/tile.
// z-batching: sAz/sBz/sCz element offsets per blockIdx.z (batch or split-K).
// Swizzle (T2): rows are 128 B; 16B-group g ^= (row&7); since chunk row =
// 64c + (tid>>3), g is per-thread constant. LDS linear; same XOR on ds_read.
// ============================================================================
template <int BN, typename OutT, bool RELU>
__global__ __launch_bounds__(512) void gemm8p_k(
    const bf16* __restrict__ A0, int lda, const bf16* __restrict__ Bt0, int ldb,
    OutT* __restrict__ C0, int ldc, int M, int N, int K,
    const float* __restrict__ bias, const float* __restrict__ resid, int ldr,
    float scale, size_t sAz, size_t sBz, size_t sCz) {
  constexpr int BM = 256;
  constexpr int DEPTH = (BN == 256) ? 2 : 3;
  constexpr int DBUF = (BM + BN) * 128;     // bytes per tile buffer
  __shared__ __align__(16) char smem[DEPTH * DBUF];

  const int tid = threadIdx.x;
  const int lane = tid & 63;
  const int wid = tid >> 6;   // 0..7

  const bf16* A = A0 + (size_t)blockIdx.z * sAz;
  const bf16* Bt = Bt0 + (size_t)blockIdx.z * sBz;
  OutT* C = C0 + (size_t)blockIdx.z * sCz;

  // T1: bijective XCD-aware remap (m204)
  const int gx = gridDim.x;
  const int nwg = gx * gridDim.y;
  int wg = blockIdx.y * gx + blockIdx.x;
  {
    const int q = nwg >> 3, r8_ = nwg & 7;
    const int xcd = wg & 7, lin = wg >> 3;
    wg = (xcd < r8_ ? xcd * (q + 1) : r8_ * (q + 1) + (xcd - r8_) * q) + lin;
  }
  const int m0 = (wg / gx) * 256;
  const int n0 = (wg % gx) * BN;

  f32x4 accQ[2][4][2][2] = {};  // BN=256: [mh][fm][nh][fn]
  f32x4 accH[4][4] = {};        // BN=128: [fm][fn]

  const int NT = K >> 6;

  if constexpr (BN == 256) {
    // ---------------- rolling reg-staged path --------------------------------
    const int wr = wid >> 2;  // 0..1 (M)
    const int wc = wid & 3;   // 0..3 (N)
    const int r8 = tid >> 3, gg = tid & 7;
    const int gsw = gg ^ (r8 & 7);      // per-thread constant swizzle group
    const bf16* pB0 = Bt + (size_t)(n0 + r8) * ldb + gsw * 8;
    const bf16* pA0 = A + (size_t)(m0 + r8) * lda + gsw * 8;
    const size_t ldb64 = (size_t)64 * ldb, lda64 = (size_t)64 * lda;
    const int lw = tid * 16;            // linear LDS lane offset

    int4 ge0, ge1, go0, go1;            // two rolling 2-chunk groups

    // prologue: stage tile 0 fully via 4 load-rounds / rolling writes (buf 0)
    ge0 = *reinterpret_cast<const int4*>(pB0);
    ge1 = *reinterpret_cast<const int4*>(pB0 + ldb64);
    go0 = *reinterpret_cast<const int4*>(pB0 + 2 * ldb64);
    go1 = *reinterpret_cast<const int4*>(pB0 + 3 * ldb64);
    *reinterpret_cast<int4*>(smem + BM * 128 + 0 * 8192 + lw) = ge0;
    *reinterpret_cast<int4*>(smem + BM * 128 + 1 * 8192 + lw) = ge1;
    ge0 = *reinterpret_cast<const int4*>(pA0);
    ge1 = *reinterpret_cast<const int4*>(pA0 + 2 * lda64);
    *reinterpret_cast<int4*>(smem + BM * 128 + 2 * 8192 + lw) = go0;
    *reinterpret_cast<int4*>(smem + BM * 128 + 3 * 8192 + lw) = go1;
    go0 = *reinterpret_cast<const int4*>(pA0 + 1 * lda64);
    go1 = *reinterpret_cast<const int4*>(pA0 + 3 * lda64);
    *reinterpret_cast<int4*>(smem + 0 * 8192 + lw) = ge0;
    *reinterpret_cast<int4*>(smem + 2 * 8192 + lw) = ge1;
    *reinterpret_cast<int4*>(smem + 1 * 8192 + lw) = go0;
    *reinterpret_cast<int4*>(smem + 3 * 8192 + lw) = go1;
    asm volatile("s_waitcnt lgkmcnt(0)" ::: "memory");
    __builtin_amdgcn_s_barrier();

    for (int t = 0; t < NT; ++t) {
      char* cur = smem + (t & 1) * DBUF;
      char* nxt = smem + ((t + 1) & 1) * DBUF;
      const char* lB = cur + BM * 128;
      const bool pf = (t + 1 < NT);
      const int tk = (t + 1) * 64;
      bf16x8 af[4][2], bf[2][2];
      // ================= p0 (mh0, nh0) =================
      if (pf) {
        ge0 = *reinterpret_cast<const int4*>(pB0 + tk);
        ge1 = *reinterpret_cast<const int4*>(pB0 + ldb64 + tk);
        __builtin_amdgcn_sched_barrier(0);
      }
#pragma unroll
      for (int fm = 0; fm < 4; ++fm) {
        const int row = wr * 128 + 0 * 64 + fm * 16 + (lane & 15);
#pragma unroll
        for (int ks = 0; ks < 2; ++ks) {
          const int g = ((ks << 2) | (lane >> 4)) ^ (row & 7);
          af[fm][ks] = *reinterpret_cast<const bf16x8*>(cur + row * 128 + g * 16);
        }
      }
#pragma unroll
      for (int fn = 0; fn < 2; ++fn) {
        const int row = wc * 64 + 0 * 32 + fn * 16 + (lane & 15);
#pragma unroll
        for (int ks = 0; ks < 2; ++ks) {
          const int g = ((ks << 2) | (lane >> 4)) ^ (row & 7);
          bf[fn][ks] = *reinterpret_cast<const bf16x8*>(lB + row * 128 + g * 16);
        }
      }
      __builtin_amdgcn_s_barrier();
      __builtin_amdgcn_s_setprio(1);
#pragma unroll
      for (int fm = 0; fm < 4; ++fm)
#pragma unroll
        for (int fn = 0; fn < 2; ++fn) {
          accQ[0][fm][0][fn] = __builtin_amdgcn_mfma_f32_16x16x32_bf16(
              af[fm][0], bf[fn][0], accQ[0][fm][0][fn], 0, 0, 0);
          accQ[0][fm][0][fn] = __builtin_amdgcn_mfma_f32_16x16x32_bf16(
              af[fm][1], bf[fn][1], accQ[0][fm][0][fn], 0, 0, 0);
        }
      __builtin_amdgcn_s_setprio(0);
      if (t > 0) {  // late write: A1,A3 of CURRENT tile (loaded prev p3)
        *reinterpret_cast<int4*>(cur + 1 * 8192 + lw) = go0;
        *reinterpret_cast<int4*>(cur + 3 * 8192 + lw) = go1;
        asm volatile("s_waitcnt lgkmcnt(0)" ::: "memory");
      }
      __builtin_amdgcn_s_barrier();
      // ================= p1 (mh0, nh1) =================
      if (pf) {
        go0 = *reinterpret_cast<const int4*>(pB0 + 2 * ldb64 + tk);
        go1 = *reinterpret_cast<const int4*>(pB0 + 3 * ldb64 + tk);
        __builtin_amdgcn_sched_barrier(0);
      }
#pragma unroll
      for (int fn = 0; fn < 2; ++fn) {
        const int row = wc * 64 + 1 * 32 + fn * 16 + (lane & 15);
#pragma unroll
        for (int ks = 0; ks < 2; ++ks) {
          const int g = ((ks << 2) | (lane >> 4)) ^ (row & 7);
          bf[fn][ks] = *reinterpret_cast<const bf16x8*>(lB + row * 128 + g * 16);
        }
      }
      __builtin_amdgcn_s_barrier();
      __builtin_amdgcn_s_setprio(1);
#pragma unroll
      for (int fm = 0; fm < 4; ++fm)
#pragma unroll
        for (int fn = 0; fn < 2; ++fn) {
          accQ[0][fm][1][fn] = __builtin_amdgcn_mfma_f32_16x16x32_bf16(
              af[fm][0], bf[fn][0], accQ[0][fm][1][fn], 0, 0, 0);
          accQ[0][fm][1][fn] = __builtin_amdgcn_mfma_f32_16x16x32_bf16(
              af[fm][1], bf[fn][1], accQ[0][fm][1][fn], 0, 0, 0);
        }
      __builtin_amdgcn_s_setprio(0);
      if (pf) {  // write B0,B1 of tile t+1
        *reinterpret_cast<int4*>(nxt + BM * 128 + 0 * 8192 + lw) = ge0;
        *reinterpret_cast<int4*>(nxt + BM * 128 + 1 * 8192 + lw) = ge1;
        asm volatile("s_waitcnt lgkmcnt(0)" ::: "memory");
      }
      __builtin_amdgcn_s_barrier();
      // ================= p2 (mh1, nh0) =================
      if (pf) {
        ge0 = *reinterpret_cast<const int4*>(pA0 + tk);
        ge1 = *reinterpret_cast<const int4*>(pA0 + 2 * lda64 + tk);
        __builtin_amdgcn_sched_barrier(0);
      }
#pragma unroll
      for (int fm = 0; fm < 4; ++fm) {
        const int row = wr * 128 + 1 * 64 + fm * 16 + (lane & 15);
#pragma unroll
        for (int ks = 0; ks < 2; ++ks) {
          const int g = ((ks << 2) | (lane >> 4)) ^ (row & 7);
          af[fm][ks] = *reinterpret_cast<const bf16x8*>(cur + row * 128 + g * 16);
        }
      }
#pragma unroll
      for (int fn = 0; fn < 2; ++fn) {
        const int row = wc * 64 + 0 * 32 + fn * 16 + (lane & 15);
#pragma unroll
        for (int ks = 0; ks < 2; ++ks) {
          const int g = ((ks << 2) | (lane >> 4)) ^ (row & 7);
          bf[fn][ks] = *reinterpret_cast<const bf16x8*>(lB + row * 128 + g * 16);
        }
      }
      __builtin_amdgcn_s_barrier();
      __builtin_amdgcn_s_setprio(1);
#pragma unroll
      for (int fm = 0; fm < 4; ++fm)
#pragma unroll
        for (int fn = 0; fn < 2; ++fn) {
          accQ[1][fm][0][fn] = __builtin_amdgcn_mfma_f32_16x16x32_bf16(
              af[fm][0], bf[fn][0], accQ[1][fm][0][fn], 0, 0, 0);
          accQ[1][fm][0][fn] = __builtin_amdgcn_mfma_f32_16x16x32_bf16(
              af[fm][1], bf[fn][1], accQ[1][fm][0][fn], 0, 0, 0);
        }
      __builtin_amdgcn_s_setprio(0);
      if (pf) {  // write B2,B3 of tile t+1
        *reinterpret_cast<int4*>(nxt + BM * 128 + 2 * 8192 + lw) = go0;
        *reinterpret_cast<int4*>(nxt + BM * 128 + 3 * 8192 + lw) = go1;
        asm volatile("s_waitcnt lgkmcnt(0)" ::: "memory");
      }
      __builtin_amdgcn_s_barrier();
      // ================= p3 (mh1, nh1) =================
      if (pf) {
        go0 = *reinterpret_cast<const int4*>(pA0 + 1 * lda64 + tk);
        go1 = *reinterpret_cast<const int4*>(pA0 + 3 * lda64 + tk);
        __builtin_amdgcn_sched_barrier(0);
      }
#pragma unroll
      for (int fn = 0; fn < 2; ++fn) {
        const int row = wc * 64 + 1 * 32 + fn * 16 + (lane & 15);
#pragma unroll
        for (int ks = 0; ks < 2; ++ks) {
          const int g = ((ks << 2) | (lane >> 4)) ^ (row & 7);
          bf[fn][ks] = *reinterpret_cast<const bf16x8*>(lB + row * 128 + g * 16);
        }
      }
      __builtin_amdgcn_s_barrier();
      __builtin_amdgcn_s_setprio(1);
#pragma unroll
      for (int fm = 0; fm < 4; ++fm)
#pragma unroll
        for (int fn = 0; fn < 2; ++fn) {
          accQ[1][fm][1][fn] = __builtin_amdgcn_mfma_f32_16x16x32_bf16(
              af[fm][0], bf[fn][0], accQ[1][fm][1][fn], 0, 0, 0);
          accQ[1][fm][1][fn] = __builtin_amdgcn_mfma_f32_16x16x32_bf16(
              af[fm][1], bf[fn][1], accQ[1][fm][1][fn], 0, 0, 0);
        }
      __builtin_amdgcn_s_setprio(0);
      if (pf) {  // write A0,A2 of tile t+1
        *reinterpret_cast<int4*>(nxt + 0 * 8192 + lw) = ge0;
        *reinterpret_cast<int4*>(nxt + 2 * 8192 + lw) = ge1;
        asm volatile("s_waitcnt lgkmcnt(0)" ::: "memory");
      }
      __builtin_amdgcn_s_barrier();
    }
  } else {
    // ---------------- gload_lds 3-deep path (r11 proven) ---------------------
    constexpr int NCH_B = BN / 64;
    constexpr int NCH = 4 + NCH_B;
    auto stage_chunk = [&](int t, int c) {
      char* base = smem + (t % DEPTH) * DBUF;
      const int r8 = tid >> 3;
      const int gg = tid & 7;
      if (c < NCH_B) {
        const int row = c * 64 + r8;
        const int g = gg ^ (row & 7);
        gload_lds16(Bt + (size_t)(n0 + row) * ldb + t * 64 + g * 8,
                    base + BM * 128 + c * 8192 + wid * 1024);
      } else {
        const int i = c - NCH_B;
        const int ca = ((i & 1) << 1) | (i >> 1);
        const int row = ca * 64 + r8;
        const int g = gg ^ (row & 7);
        gload_lds16(A + (size_t)(m0 + row) * lda + t * 64 + g * 8,
                    base + ca * 8192 + wid * 1024);
      }
    };
#pragma unroll
    for (int c = 0; c < NCH; ++c) stage_chunk(0, c);
#pragma unroll
    for (int c = 0; c < NCH; ++c) stage_chunk(1, c);
    asm volatile("s_waitcnt vmcnt(6)" ::: "memory");
    __builtin_amdgcn_s_barrier();

    for (int t = 0; t < NT; ++t) {
      const char* lA = smem + (t % DEPTH) * DBUF;
      const char* lB = lA + BM * 128;
      const int wr = wid >> 1;
      const int wc = wid & 1;
#pragma unroll
      for (int p = 0; p < 2; ++p) {
        bf16x8 af[4], bf[4];
#pragma unroll
        for (int fm = 0; fm < 4; ++fm) {
          const int row = wr * 64 + fm * 16 + (lane & 15);
          const int g = ((p << 2) | (lane >> 4)) ^ (row & 7);
          af[fm] = *reinterpret_cast<const bf16x8*>(lA + row * 128 + g * 16);
        }
#pragma unroll
        for (int fn = 0; fn < 4; ++fn) {
          const int row = wc * 64 + fn * 16 + (lane & 15);
          const int g = ((p << 2) | (lane >> 4)) ^ (row & 7);
          bf[fn] = *reinterpret_cast<const bf16x8*>(lB + row * 128 + g * 16);
        }
        if (t + 2 < NT) {
#pragma unroll
          for (int c = 0; c < 3; ++c) stage_chunk(t + 2, p * 3 + c);
        }
        __builtin_amdgcn_s_barrier();
        __builtin_amdgcn_s_setprio(1);
#pragma unroll
        for (int fm = 0; fm < 4; ++fm)
#pragma unroll
          for (int fn = 0; fn < 4; ++fn)
            accH[fm][fn] = __builtin_amdgcn_mfma_f32_16x16x32_bf16(
                af[fm], bf[fn], accH[fm][fn], 0, 0, 0);
        __builtin_amdgcn_s_setprio(0);
        if (p == 1) {
          if (t + 2 < NT) asm volatile("s_waitcnt vmcnt(6)" ::: "memory");
          else            asm volatile("s_waitcnt vmcnt(0)" ::: "memory");
        }
        __builtin_amdgcn_s_barrier();
      }
    }
  }

  // --------------------------- epilogue -------------------------------------
  if constexpr (BN == 256) {
    const int wr = wid >> 2, wc = wid & 3;
#pragma unroll
    for (int mh = 0; mh < 2; ++mh)
#pragma unroll
      for (int nh = 0; nh < 2; ++nh)
#pragma unroll
        for (int fn = 0; fn < 2; ++fn) {
          const int col = n0 + wc * 64 + nh * 32 + fn * 16 + (lane & 15);
          const float bv = bias ? bias[col] : 0.0f;
#pragma unroll
          for (int fm = 0; fm < 4; ++fm)
#pragma unroll
            for (int i = 0; i < 4; ++i) {
              const int row = m0 + wr * 128 + mh * 64 + fm * 16 + (lane >> 4) * 4 + i;
              float v = accQ[mh][fm][nh][fn][i] * scale + bv;
              if (resid) v += resid[(size_t)row * ldr + col];
              if (RELU) v = fmaxf(v, 0.0f);
              C[(size_t)row * ldc + col] = (OutT)v;
            }
        }
  } else {
    const int wr = wid >> 1, wc = wid & 1;
#pragma unroll
    for (int fn = 0; fn < 4; ++fn) {
      const int col = n0 + wc * 64 + fn * 16 + (lane & 15);
      const float bv = bias ? bias[col] : 0.0f;
#pragma unroll
      for (int fm = 0; fm < 4; ++fm)
#pragma unroll
        for (int i = 0; i < 4; ++i) {
          const int row = m0 + wr * 64 + fm * 16 + (lane >> 4) * 4 + i;
          float v = accH[fm][fn][i] * scale + bv;
          if (resid) v += resid[(size_t)row * ldr + col];
          if (RELU) v = fmaxf(v, 0.0f);
          C[(size_t)row * ldc + col] = (OutT)v;
        }
    }
  }
}

// =============================================================================
extern "C" void kernel_launch(void* const* d_in, const int* in_sizes, int n_in,
                              void* d_out, int out_size, void* d_ws,
                              size_t ws_size, hipStream_t stream) {
  const float* src = (const float*)d_in[0];
  const float* Wq_w = (const float*)d_in[1];
  const float* Wq_b = (const float*)d_in[2];
  const float* Wk_w = (const float*)d_in[3];
  const float* Wk_b = (const float*)d_in[4];
  const float* Wv_w = (const float*)d_in[5];
  const float* Wv_b = (const float*)d_in[6];
  const float* Wo_w = (const float*)d_in[7];
  const float* Wo_b = (const float*)d_in[8];
  const float* W1_w = (const float*)d_in[9];
  const float* W1_b = (const float*)d_in[10];
  const float* W2_w = (const float*)d_in[11];
  const float* W2_b = (const float*)d_in[12];
  const float* g1 = (const float*)d_in[13];
  const float* b1 = (const float*)d_in[14];
  const float* g2 = (const float*)d_in[15];
  const float* b2 = (const float*)d_in[16];
  const float* g3 = (const float*)d_in[17];
  const float* b3 = (const float*)d_in[18];
  float* out = (float*)d_out;
  (void)ws_size; (void)in_sizes; (void)n_in; (void)out_size;

  // ---- workspace layout: peak 120 MB, heavy aliasing (lifetimes verified) ---
  const size_t MB = 1ull << 20;
  char* ws = (char*)d_ws;
  bf16* wqkv = (bf16*)(ws + 0 * MB);      // 6 MB [wq|wk|wv stacked rows]
  bf16* wo = (bf16*)(ws + 6 * MB);        // 2 MB
  bf16* w1 = (bf16*)(ws + 8 * MB);        // 8 MB
  bf16* w2 = (bf16*)(ws + 16 * MB);       // 8 MB
  bf16* Cqkv = (bf16*)(ws + 24 * MB);     // 48 MB [8192][3072]
  bf16* Vt = (bf16*)(ws + 72 * MB);       // 16 MB [b][E][S]
  bf16* scoresB = (bf16*)(ws + 88 * MB);  // 32 MB [88..120)
  bf16* xln = (bf16*)(ws + 88 * MB);      // 16 MB (dead before scores written)
  float* bqkv = (float*)(ws + 104 * MB);  // 12 KB (dead before scores written)
  bf16* ctx = Cqkv;                       // alias (Cqkv dead after transpose)
  bf16* pw = (bf16*)(ws + 40 * MB);       // 32 MB: Wo split-K partials
  bf16* hn = scoresB;                     // alias (scores dead after PV)
  bf16* f1 = (bf16*)(ws + 24 * MB);       // 64 MB [24..88)
  bf16* pp = (bf16*)(ws + 88 * MB);       // 32 MB: FF2 split-K partials
  float* h = out;                         // residual stream lives in d_out

  // weights -> bf16 (QKV stacked), biases stacked via d2d copies
  cvt_k<<<(E_DIM * E_DIM / 4 + 255) / 256, 256, 0, stream>>>(Wq_w, wqkv, E_DIM * E_DIM / 4);
  cvt_k<<<(E_DIM * E_DIM / 4 + 255) / 256, 256, 0, stream>>>(Wk_w, wqkv + (size_t)E_DIM * E_DIM, E_DIM * E_DIM / 4);
  cvt_k<<<(E_DIM * E_DIM / 4 + 255) / 256, 256, 0, stream>>>(Wv_w, wqkv + 2 * (size_t)E_DIM * E_DIM, E_DIM * E_DIM / 4);
  cvt_k<<<(E_DIM * E_DIM / 4 + 255) / 256, 256, 0, stream>>>(Wo_w, wo, E_DIM * E_DIM / 4);
  cvt_k<<<(FF_DIM * E_DIM / 4 + 255) / 256, 256, 0, stream>>>(W1_w, w1, FF_DIM * E_DIM / 4);
  cvt_k<<<(FF_DIM * E_DIM / 4 + 255) / 256, 256, 0, stream>>>(W2_w, w2, FF_DIM * E_DIM / 4);
  hipMemcpyAsync(bqkv, Wq_b, E_DIM * 4, hipMemcpyDeviceToDevice, stream);
  hipMemcpyAsync(bqkv + E_DIM, Wk_b, E_DIM * 4, hipMemcpyDeviceToDevice, stream);
  hipMemcpyAsync(bqkv + 2 * E_DIM, Wv_b, E_DIM * 4, hipMemcpyDeviceToDevice, stream);

  // LN1
  layernorm_k<bf16><<<NTOK, 256, 0, stream>>>(src, xln, g1, b1);

  // QKV fused: [8192][3072] = xln @ wqkv^T + bqkv
  dim3 gQKV(QKV_N / 256, NTOK / 256);
  gemm8p_k<256, bf16, false><<<gQKV, 512, 0, stream>>>(
      xln, E_DIM, wqkv, E_DIM, Cqkv, QKV_N, NTOK, QKV_N, E_DIM,
      bqkv, nullptr, 0, 1.0f, 0, 0, 0);

  // scores[b] = (Q K^T) / 32 -> bf16, z-batched (Q,K strided views of Cqkv)
  dim3 gSc(S_DIM / 256, S_DIM / 256, B_DIM);
  gemm8p_k<256, bf16, false><<<gSc, 512, 0, stream>>>(
      Cqkv, QKV_N, Cqkv + E_DIM, QKV_N, scoresB, S_DIM, S_DIM, S_DIM, E_DIM,
      nullptr, nullptr, 0, 1.0f / 32.0f,
      (size_t)S_DIM * QKV_N, (size_t)S_DIM * QKV_N, (size_t)S_DIM * S_DIM);

  // softmax rows, in-place bf16
  softmax_k<<<B_DIM * S_DIM, 256, 0, stream>>>(scoresB);

  // V transpose per batch (V = cols [2048..3072) of Cqkv)
  transpose_k<<<dim3(E_DIM / 32, S_DIM / 32, B_DIM), 256, 0, stream>>>(
      Cqkv + 2 * E_DIM, QKV_N, (size_t)S_DIM * QKV_N, Vt);

  // ctx[b] = P V, z-batched (writes over Cqkv start; P + Vt still live)
  dim3 gPV(E_DIM / 128, S_DIM / 256, B_DIM);
  gemm8p_k<128, bf16, false><<<gPV, 512, 0, stream>>>(
      scoresB, S_DIM, Vt, S_DIM, ctx, E_DIM, S_DIM, E_DIM, S_DIM,
      nullptr, nullptr, 0, 1.0f,
      (size_t)S_DIM * S_DIM, (size_t)S_DIM * E_DIM, (size_t)S_DIM * E_DIM);

  // Wo split-K=2, ONE dispatch: pw[z] = ctx[:, zK:] @ wo[:, zK:]^T
  dim3 gWo(E_DIM / 256, NTOK / 256, 2);
  gemm8p_k<256, bf16, false><<<gWo, 512, 0, stream>>>(
      ctx, E_DIM, wo, E_DIM, pw, E_DIM, NTOK, E_DIM, E_DIM / 2,
      nullptr, nullptr, 0, 1.0f,
      (size_t)(E_DIM / 2), (size_t)(E_DIM / 2), (size_t)NTOK * E_DIM);

  // LN2 fused with Wo reduce: h = src + pw0 + pw1 + bo; hn = LN(h)
  ln2_fused_k<<<NTOK, 256, 0, stream>>>(
      src, pw, pw + (size_t)NTOK * E_DIM, Wo_b, h, hn, g2, b2);

  // f1 = relu(hn @ W1^T + b1)
  dim3 gF1(FF_DIM / 256, NTOK / 256);
  gemm8p_k<256, bf16, true><<<gF1, 512, 0, stream>>>(
      hn, E_DIM, w1, E_DIM, f1, FF_DIM, NTOK, FF_DIM, E_DIM,
      W1_b, nullptr, 0, 1.0f, 0, 0, 0);

  // FF2 split-K=2, ONE dispatch: pp[z] = f1[:, zK:] @ w2[:, zK:]^T
  dim3 gF2(E_DIM / 256, NTOK / 256, 2);
  gemm8p_k<256, bf16, false><<<gF2, 512, 0, stream>>>(
      f1, FF_DIM, w2, FF_DIM, pp, E_DIM, NTOK, E_DIM, FF_DIM / 2,
      nullptr, nullptr, 0, 1.0f,
      (size_t)(FF_DIM / 2), (size_t)(FF_DIM / 2), (size_t)NTOK * E_DIM);

  // LN3 fused with the split-K reduce: out = LN(h + p0 + p1 + b2)
  ln3_fused_k<<<NTOK, 256, 0, stream>>>(
      h, pp, pp + (size_t)NTOK * E_DIM, W2_b, out, g3, b3);
}

// Round 13
// 382.876 us; speedup vs baseline: 1.1180x; 1.1180x over previous
//
#include <hip/hip_runtime.h>
#include <cstdint>
#include <cmath>

#define E_DIM 1024
#define FF_DIM 4096
#define B_DIM 4
#define S_DIM 2048
#define NTOK (B_DIM * S_DIM)  // 8192
#define QKV_N 3072

typedef __bf16 bf16;
typedef __attribute__((ext_vector_type(8))) __bf16 bf16x8;
typedef __attribute__((ext_vector_type(4))) float f32x4;

// ---- async global->LDS, 16B per lane (HW: dest = wave-uniform base + lane*16)
__device__ __forceinline__ void gload_lds16(const void* g, void* l) {
  __builtin_amdgcn_global_load_lds(
      (const __attribute__((address_space(1))) unsigned int*)g,
      (__attribute__((address_space(3))) unsigned int*)l, 16, 0, 0);
}

__device__ __forceinline__ float waveRedSum(float v) {
#pragma unroll
  for (int o = 32; o > 0; o >>= 1) v += __shfl_xor(v, o, 64);
  return v;
}
__device__ __forceinline__ float waveRedMax(float v) {
#pragma unroll
  for (int o = 32; o > 0; o >>= 1) v = fmaxf(v, __shfl_xor(v, o, 64));
  return v;
}

// ============================================================================
// prep_k: ONE dispatch replacing {LN1, 6x weight cvt, 3x bias memcpy}.
// Block ranges:
//   [0, 8192)            LN1 rows: xln = LN(src, g1, b1) (bf16)
//   [8192, 8192+12288)   fp32->bf16 weight converts (1024 f4-elems per block)
//   [20480, 20483)       bias gathers into bqkv
// ============================================================================
#define PREP_LN 8192
#define PREP_CVT (PREP_LN + 12288)
__global__ __launch_bounds__(256) void prep_k(
    const float* __restrict__ src, const float* __restrict__ Wq_w,
    const float* __restrict__ Wk_w, const float* __restrict__ Wv_w,
    const float* __restrict__ Wo_w, const float* __restrict__ W1_w,
    const float* __restrict__ W2_w, const float* __restrict__ Wq_b,
    const float* __restrict__ Wk_b, const float* __restrict__ Wv_b,
    const float* __restrict__ g1, const float* __restrict__ b1,
    bf16* __restrict__ wqkv, bf16* __restrict__ wo, bf16* __restrict__ w1,
    bf16* __restrict__ w2, float* __restrict__ bqkv, bf16* __restrict__ xln) {
  const int blk = blockIdx.x;
  const int tid = threadIdx.x;
  if (blk < PREP_LN) {
    // ---- LN1 row ----
    const int row = blk;
    const float4 v = reinterpret_cast<const float4*>(src + (size_t)row * E_DIM)[tid];
    float s = v.x + v.y + v.z + v.w;
    float q = v.x * v.x + v.y * v.y + v.z * v.z + v.w * v.w;
    s = waveRedSum(s);
    q = waveRedSum(q);
    __shared__ float sa[4], sb[4];
    const int lane = tid & 63, wid = tid >> 6;
    if (lane == 0) { sa[wid] = s; sb[wid] = q; }
    __syncthreads();
    s = sa[0] + sa[1] + sa[2] + sa[3];
    q = sb[0] + sb[1] + sb[2] + sb[3];
    const float mean = s * (1.0f / E_DIM);
    const float var = q * (1.0f / E_DIM) - mean * mean;
    const float rstd = rsqrtf(var + 1e-5f);
    const int c = tid * 4;
    bf16* op = xln + (size_t)row * E_DIM + c;
    const float vv[4] = {v.x, v.y, v.z, v.w};
#pragma unroll
    for (int j = 0; j < 4; ++j)
      op[j] = (bf16)((vv[j] - mean) * rstd * g1[c + j] + b1[c + j]);
  } else if (blk < PREP_CVT) {
    // ---- weight converts: each block handles 1024 float4 (4096 elems) ----
    int l = blk - PREP_LN;
    const float* in;
    bf16* out;
    if (l < 1024)        { in = Wq_w; out = wqkv;                                }
    else if (l < 2048)   { in = Wk_w; out = wqkv + (size_t)E_DIM * E_DIM;  l -= 1024; }
    else if (l < 3072)   { in = Wv_w; out = wqkv + 2 * (size_t)E_DIM * E_DIM; l -= 2048; }
    else if (l < 4096)   { in = Wo_w; out = wo;   l -= 3072; }
    else if (l < 8192)   { in = W1_w; out = w1;   l -= 4096; }
    else                 { in = W2_w; out = w2;   l -= 8192; }
    const size_t i = (size_t)l * 256 + tid;
    float4 v = reinterpret_cast<const float4*>(in)[i];
    bf16* o = out + i * 4;
    o[0] = (bf16)v.x; o[1] = (bf16)v.y; o[2] = (bf16)v.z; o[3] = (bf16)v.w;
  } else {
    // ---- bias gathers: 1 block per 1024-float bias ----
    const int bsel = blk - PREP_CVT;
    const float* in = (bsel == 0) ? Wq_b : (bsel == 1) ? Wk_b : Wv_b;
    reinterpret_cast<float4*>(bqkv + bsel * E_DIM)[tid] =
        reinterpret_cast<const float4*>(in)[tid];
  }
}

// ---- LN2 fused with Wo split-K reduce: x = src + p0 + p1 + bo;
// h(d_out,fp32) = x;  hn(bf16) = LN(x, g2, b2) --------------------------------
__global__ __launch_bounds__(256) void ln2_fused_k(
    const float* __restrict__ src, const bf16* __restrict__ p0,
    const bf16* __restrict__ p1, const float* __restrict__ bo,
    float* __restrict__ h, bf16* __restrict__ hn,
    const float* __restrict__ g, const float* __restrict__ b) {
  const int row = blockIdx.x;
  const int tid = threadIdx.x;
  const int c = tid * 4;
  const float4 sv = reinterpret_cast<const float4*>(src + (size_t)row * E_DIM)[tid];
  const ushort4 a0 = reinterpret_cast<const ushort4*>(p0 + (size_t)row * E_DIM)[tid];
  const ushort4 a1 = reinterpret_cast<const ushort4*>(p1 + (size_t)row * E_DIM)[tid];
  const float4 bv = reinterpret_cast<const float4*>(bo)[tid];
  auto b2f = [](unsigned short u) {
    union { unsigned int i; float f; } t; t.i = (unsigned int)u << 16; return t.f;
  };
  float x[4];
  x[0] = sv.x + b2f(a0.x) + b2f(a1.x) + bv.x;
  x[1] = sv.y + b2f(a0.y) + b2f(a1.y) + bv.y;
  x[2] = sv.z + b2f(a0.z) + b2f(a1.z) + bv.z;
  x[3] = sv.w + b2f(a0.w) + b2f(a1.w) + bv.w;
  float4 hv = {x[0], x[1], x[2], x[3]};
  reinterpret_cast<float4*>(h + (size_t)row * E_DIM)[tid] = hv;
  float s = x[0] + x[1] + x[2] + x[3];
  float q = x[0] * x[0] + x[1] * x[1] + x[2] * x[2] + x[3] * x[3];
  s = waveRedSum(s);
  q = waveRedSum(q);
  __shared__ float sa[4], sb[4];
  const int lane = tid & 63, wid = tid >> 6;
  if (lane == 0) { sa[wid] = s; sb[wid] = q; }
  __syncthreads();
  s = sa[0] + sa[1] + sa[2] + sa[3];
  q = sb[0] + sb[1] + sb[2] + sb[3];
  const float mean = s * (1.0f / E_DIM);
  const float var = q * (1.0f / E_DIM) - mean * mean;
  const float rstd = rsqrtf(var + 1e-5f);
  bf16* op = hn + (size_t)row * E_DIM + c;
#pragma unroll
  for (int j = 0; j < 4; ++j)
    op[j] = (bf16)((x[j] - mean) * rstd * g[c + j] + b[c + j]);
}

// ---- LN3 fused with FF2 split-K reduce: x = h + p0 + p1 + bias2; LN -> out --
__global__ __launch_bounds__(256) void ln3_fused_k(
    const float* __restrict__ h, const bf16* __restrict__ p0,
    const bf16* __restrict__ p1, const float* __restrict__ bias2,
    float* __restrict__ out, const float* __restrict__ g,
    const float* __restrict__ b) {
  const int row = blockIdx.x;
  const int tid = threadIdx.x;
  const int c = tid * 4;
  const float4 hv = reinterpret_cast<const float4*>(h + (size_t)row * E_DIM)[tid];
  const ushort4 a0 = reinterpret_cast<const ushort4*>(p0 + (size_t)row * E_DIM)[tid];
  const ushort4 a1 = reinterpret_cast<const ushort4*>(p1 + (size_t)row * E_DIM)[tid];
  const float4 bv = reinterpret_cast<const float4*>(bias2)[tid];
  auto b2f = [](unsigned short u) {
    union { unsigned int i; float f; } t; t.i = (unsigned int)u << 16; return t.f;
  };
  float x[4];
  x[0] = hv.x + b2f(a0.x) + b2f(a1.x) + bv.x;
  x[1] = hv.y + b2f(a0.y) + b2f(a1.y) + bv.y;
  x[2] = hv.z + b2f(a0.z) + b2f(a1.z) + bv.z;
  x[3] = hv.w + b2f(a0.w) + b2f(a1.w) + bv.w;
  float s = x[0] + x[1] + x[2] + x[3];
  float q = x[0] * x[0] + x[1] * x[1] + x[2] * x[2] + x[3] * x[3];
  s = waveRedSum(s);
  q = waveRedSum(q);
  __shared__ float sa[4], sb[4];
  const int lane = tid & 63, wid = tid >> 6;
  if (lane == 0) { sa[wid] = s; sb[wid] = q; }
  __syncthreads();
  s = sa[0] + sa[1] + sa[2] + sa[3];
  q = sb[0] + sb[1] + sb[2] + sb[3];
  const float mean = s * (1.0f / E_DIM);
  const float var = q * (1.0f / E_DIM) - mean * mean;
  const float rstd = rsqrtf(var + 1e-5f);
  float* op = out + (size_t)row * E_DIM + c;
#pragma unroll
  for (int j = 0; j < 4; ++j)
    op[j] = (x[j] - mean) * rstd * g[c + j] + b[c + j];
}

// ---------------- row softmax over S=2048, in-place bf16 ---------------------
__global__ __launch_bounds__(256) void softmax_k(bf16* __restrict__ scores) {
  const int row = blockIdx.x;
  bf16* rp = scores + (size_t)row * S_DIM;
  const int tid = threadIdx.x;
  const int lane = tid & 63, wid = tid >> 6;
  bf16x8 v8 = *reinterpret_cast<const bf16x8*>(rp + tid * 8);
  float v[8];
#pragma unroll
  for (int j = 0; j < 8; ++j) v[j] = (float)v8[j];
  float mx = v[0];
#pragma unroll
  for (int j = 1; j < 8; ++j) mx = fmaxf(mx, v[j]);
  mx = waveRedMax(mx);
  __shared__ float sm_[4], ss_[4];
  if (lane == 0) sm_[wid] = mx;
  __syncthreads();
  mx = fmaxf(fmaxf(sm_[0], sm_[1]), fmaxf(sm_[2], sm_[3]));
  float e[8];
  float s = 0.f;
#pragma unroll
  for (int j = 0; j < 8; ++j) { e[j] = __expf(v[j] - mx); s += e[j]; }
  s = waveRedSum(s);
  if (lane == 0) ss_[wid] = s;
  __syncthreads();
  s = ss_[0] + ss_[1] + ss_[2] + ss_[3];
  const float inv = 1.0f / s;
  bf16x8 o;
#pragma unroll
  for (int j = 0; j < 8; ++j) o[j] = (bf16)(e[j] * inv);
  *reinterpret_cast<bf16x8*>(rp + tid * 8) = o;
}

// -------- bf16 transpose [S][ld_in] cols -> [E][S] per batch (strided in) ----
__global__ __launch_bounds__(256) void transpose_k(const bf16* __restrict__ in,
                                                   int ld_in, size_t bstride_in,
                                                   bf16* __restrict__ out) {
  __shared__ bf16 t[32][33];
  const int b = blockIdx.z;
  const bf16* ip = in + (size_t)b * bstride_in;
  bf16* op = out + (size_t)b * S_DIM * E_DIM;
  const int e0 = blockIdx.x * 32, s0 = blockIdx.y * 32;
  const int tx = threadIdx.x & 31, ty = threadIdx.x >> 5;  // 32 x 8
#pragma unroll
  for (int r = 0; r < 32; r += 8)
    t[ty + r][tx] = ip[(size_t)(s0 + ty + r) * ld_in + e0 + tx];
  __syncthreads();
#pragma unroll
  for (int r = 0; r < 32; r += 8)
    op[(size_t)(e0 + ty + r) * S_DIM + s0 + tx] = t[tx][ty + r];
}

// ============================================================================
// 256xBN 8-wave GEMM, BK=64, phase schedule with counted vmcnt (r11 proven).
// C = scale*(A @ Bt^T) + bias (+resid) (+relu).  A: MxK (lda), Bt: NxK (ldb).
// BN=256: 2-deep dbuf, 4 phases/tile (C-quadrant), LDS 128 KB, wave=128x64
//   (2Mx4N). Waits: mid p1 vmcnt(4), boundary p3 vmcnt(2).
// BN=128: 3-deep bufs, 2 phases/tile (K-half),     LDS 144 KB, wave= 64x64
//   (4Mx2N). Stage tile t+2 (3 chunks/phase); ONE boundary wait vmcnt(6)/tile.
// z-batching: sAz/sBz/sCz are ELEMENT offsets per blockIdx.z — used both for
// per-batch strides (attention) and for SPLIT-K (sAz=sBz=K, sCz=M*N).
// Swizzle (T2): rows are 128 B; 16B-group g ^= (row&7); inverse applied on
// global source (gload_lds dest stays linear), same XOR on ds_read.
// ============================================================================
template <int BN, typename OutT, bool RELU>
__global__ __launch_bounds__(512) void gemm8p_k(
    const bf16* __restrict__ A0, int lda, const bf16* __restrict__ Bt0, int ldb,
    OutT* __restrict__ C0, int ldc, int M, int N, int K,
    const float* __restrict__ bias, const float* __restrict__ resid, int ldr,
    float scale, size_t sAz, size_t sBz, size_t sCz) {
  constexpr int BM = 256;
  constexpr int NCH_B = BN / 64;            // B chunks: 4 or 2
  constexpr int NCH = 4 + NCH_B;            // total chunks: 8 or 6
  constexpr int DEPTH = (BN == 256) ? 2 : 3;
  constexpr int DBUF = (BM + BN) * 128;     // bytes per tile buffer
  __shared__ __align__(16) char smem[DEPTH * DBUF];

  const int tid = threadIdx.x;
  const int lane = tid & 63;
  const int wid = tid >> 6;   // 0..7

  const bf16* A = A0 + (size_t)blockIdx.z * sAz;
  const bf16* Bt = Bt0 + (size_t)blockIdx.z * sBz;
  OutT* C = C0 + (size_t)blockIdx.z * sCz;

  // T1: bijective XCD-aware remap (m204)
  const int gx = gridDim.x;
  const int nwg = gx * gridDim.y;
  int wg = blockIdx.y * gx + blockIdx.x;
  {
    const int q = nwg >> 3, r8_ = nwg & 7;
    const int xcd = wg & 7, lin = wg >> 3;
    wg = (xcd < r8_ ? xcd * (q + 1) : r8_ * (q + 1) + (xcd - r8_) * q) + lin;
  }
  const int m0 = (wg / gx) * 256;
  const int n0 = (wg % gx) * BN;

  // stage chunk c of tile t into buffer t%DEPTH. Linear LDS dest; source
  // inverse-swizzled.
  auto stage_chunk = [&](int t, int c) {
    char* base = smem + (t % DEPTH) * DBUF;
    const int r8 = tid >> 3;  // 0..63 row within chunk
    const int gg = tid & 7;   // 16B group
    if (c < NCH_B) {
      const int row = c * 64 + r8;
      const int g = gg ^ (row & 7);
      gload_lds16(Bt + (size_t)(n0 + row) * ldb + t * 64 + g * 8,
                  base + BM * 128 + c * 8192 + wid * 1024);
    } else {
      const int i = c - NCH_B;
      const int ca = ((i & 1) << 1) | (i >> 1);  // order A0,A2,A1,A3
      const int row = ca * 64 + r8;
      const int g = gg ^ (row & 7);
      gload_lds16(A + (size_t)(m0 + row) * lda + t * 64 + g * 8,
                  base + ca * 8192 + wid * 1024);
    }
  };

  f32x4 accQ[2][4][2][2] = {};  // BN=256: [mh][fm][nh][fn]
  f32x4 accH[4][4] = {};        // BN=128: [fm][fn]

  const int NT = K >> 6;
  // prologue
  if constexpr (BN == 256) {
#pragma unroll
    for (int c = 0; c < NCH; ++c) stage_chunk(0, c);
    asm volatile("s_waitcnt vmcnt(2)" ::: "memory");
  } else {
#pragma unroll
    for (int c = 0; c < NCH; ++c) stage_chunk(0, c);
#pragma unroll
    for (int c = 0; c < NCH; ++c) stage_chunk(1, c);
    asm volatile("s_waitcnt vmcnt(6)" ::: "memory");  // tile0 landed
  }
  __builtin_amdgcn_s_barrier();

  for (int t = 0; t < NT; ++t) {
    const char* lA = smem + (t % DEPTH) * DBUF;
    const char* lB = lA + BM * 128;
    if constexpr (BN == 256) {
      const int wr = wid >> 2;  // 0..1 (M)
      const int wc = wid & 3;   // 0..3 (N)
      bf16x8 af[4][2];
      bf16x8 bfv[2][2][2];
#pragma unroll
      for (int p = 0; p < 4; ++p) {
        const int mh = p >> 1, nh = p & 1;
        if (p == 0 || p == 2) {
#pragma unroll
          for (int fm = 0; fm < 4; ++fm) {
            const int row = wr * 128 + mh * 64 + fm * 16 + (lane & 15);
#pragma unroll
            for (int ks = 0; ks < 2; ++ks) {
              const int g = ((ks << 2) | (lane >> 4)) ^ (row & 7);
              af[fm][ks] = *reinterpret_cast<const bf16x8*>(lA + row * 128 + g * 16);
            }
          }
        }
        if (p < 2) {
#pragma unroll
          for (int fn = 0; fn < 2; ++fn) {
            const int row = wc * 64 + p * 32 + fn * 16 + (lane & 15);
#pragma unroll
            for (int ks = 0; ks < 2; ++ks) {
              const int g = ((ks << 2) | (lane >> 4)) ^ (row & 7);
              bfv[p][fn][ks] =
                  *reinterpret_cast<const bf16x8*>(lB + row * 128 + g * 16);
            }
          }
        }
        if (t + 1 < NT) {
#pragma unroll
          for (int c = 0; c < 2; ++c) stage_chunk(t + 1, p * 2 + c);
        }
        __builtin_amdgcn_s_barrier();
        __builtin_amdgcn_s_setprio(1);
#pragma unroll
        for (int fm = 0; fm < 4; ++fm)
#pragma unroll
          for (int fn = 0; fn < 2; ++fn) {
            accQ[mh][fm][nh][fn] = __builtin_amdgcn_mfma_f32_16x16x32_bf16(
                af[fm][0], bfv[nh][fn][0], accQ[mh][fm][nh][fn], 0, 0, 0);
            accQ[mh][fm][nh][fn] = __builtin_amdgcn_mfma_f32_16x16x32_bf16(
                af[fm][1], bfv[nh][fn][1], accQ[mh][fm][nh][fn], 0, 0, 0);
          }
        __builtin_amdgcn_s_setprio(0);
        if (p == 1) {
          if (t + 1 < NT) asm volatile("s_waitcnt vmcnt(4)" ::: "memory");
          else            asm volatile("s_waitcnt vmcnt(0)" ::: "memory");
        }
        if (p == 3) {
          asm volatile("s_waitcnt vmcnt(2)" ::: "memory");  // next tile's head
        }
        __builtin_amdgcn_s_barrier();
      }
    } else {
      // BN=128, 4Mx2N waves, wave tile 64x64, phases = K-halves (ks)
      const int wr = wid >> 1;  // 0..3 (M)
      const int wc = wid & 1;   // 0..1 (N)
#pragma unroll
      for (int p = 0; p < 2; ++p) {
        bf16x8 af[4], bf[4];
#pragma unroll
        for (int fm = 0; fm < 4; ++fm) {
          const int row = wr * 64 + fm * 16 + (lane & 15);
          const int g = ((p << 2) | (lane >> 4)) ^ (row & 7);
          af[fm] = *reinterpret_cast<const bf16x8*>(lA + row * 128 + g * 16);
        }
#pragma unroll
        for (int fn = 0; fn < 4; ++fn) {
          const int row = wc * 64 + fn * 16 + (lane & 15);
          const int g = ((p << 2) | (lane >> 4)) ^ (row & 7);
          bf[fn] = *reinterpret_cast<const bf16x8*>(lB + row * 128 + g * 16);
        }
        if (t + 2 < NT) {
#pragma unroll
          for (int c = 0; c < 3; ++c) stage_chunk(t + 2, p * 3 + c);
        }
        __builtin_amdgcn_s_barrier();
        __builtin_amdgcn_s_setprio(1);
#pragma unroll
        for (int fm = 0; fm < 4; ++fm)
#pragma unroll
          for (int fn = 0; fn < 4; ++fn)
            accH[fm][fn] = __builtin_amdgcn_mfma_f32_16x16x32_bf16(
                af[fm], bf[fn], accH[fm][fn], 0, 0, 0);
        __builtin_amdgcn_s_setprio(0);
        if (p == 1) {
          if (t + 2 < NT) asm volatile("s_waitcnt vmcnt(6)" ::: "memory");
          else            asm volatile("s_waitcnt vmcnt(0)" ::: "memory");
        }
        __builtin_amdgcn_s_barrier();
      }
    }
  }

  // --------------------------- epilogue -------------------------------------
  if constexpr (BN == 256) {
    const int wr = wid >> 2, wc = wid & 3;
#pragma unroll
    for (int mh = 0; mh < 2; ++mh)
#pragma unroll
      for (int nh = 0; nh < 2; ++nh)
#pragma unroll
        for (int fn = 0; fn < 2; ++fn) {
          const int col = n0 + wc * 64 + nh * 32 + fn * 16 + (lane & 15);
          const float bv = bias ? bias[col] : 0.0f;
#pragma unroll
          for (int fm = 0; fm < 4; ++fm)
#pragma unroll
            for (int i = 0; i < 4; ++i) {
              const int row = m0 + wr * 128 + mh * 64 + fm * 16 + (lane >> 4) * 4 + i;
              float v = accQ[mh][fm][nh][fn][i] * scale + bv;
              if (resid) v += resid[(size_t)row * ldr + col];
              if (RELU) v = fmaxf(v, 0.0f);
              C[(size_t)row * ldc + col] = (OutT)v;
            }
        }
  } else {
    const int wr = wid >> 1, wc = wid & 1;
#pragma unroll
    for (int fn = 0; fn < 4; ++fn) {
      const int col = n0 + wc * 64 + fn * 16 + (lane & 15);
      const float bv = bias ? bias[col] : 0.0f;
#pragma unroll
      for (int fm = 0; fm < 4; ++fm)
#pragma unroll
        for (int i = 0; i < 4; ++i) {
          const int row = m0 + wr * 64 + fm * 16 + (lane >> 4) * 4 + i;
          float v = accH[fm][fn][i] * scale + bv;
          if (resid) v += resid[(size_t)row * ldr + col];
          if (RELU) v = fmaxf(v, 0.0f);
          C[(size_t)row * ldc + col] = (OutT)v;
        }
    }
  }
}

// =============================================================================
extern "C" void kernel_launch(void* const* d_in, const int* in_sizes, int n_in,
                              void* d_out, int out_size, void* d_ws,
                              size_t ws_size, hipStream_t stream) {
  const float* src = (const float*)d_in[0];
  const float* Wq_w = (const float*)d_in[1];
  const float* Wq_b = (const float*)d_in[2];
  const float* Wk_w = (const float*)d_in[3];
  const float* Wk_b = (const float*)d_in[4];
  const float* Wv_w = (const float*)d_in[5];
  const float* Wv_b = (const float*)d_in[6];
  const float* Wo_w = (const float*)d_in[7];
  const float* Wo_b = (const float*)d_in[8];
  const float* W1_w = (const float*)d_in[9];
  const float* W1_b = (const float*)d_in[10];
  const float* W2_w = (const float*)d_in[11];
  const float* W2_b = (const float*)d_in[12];
  const float* g1 = (const float*)d_in[13];
  const float* b1 = (const float*)d_in[14];
  const float* g2 = (const float*)d_in[15];
  const float* b2 = (const float*)d_in[16];
  const float* g3 = (const float*)d_in[17];
  const float* b3 = (const float*)d_in[18];
  float* out = (float*)d_out;
  (void)ws_size; (void)in_sizes; (void)n_in; (void)out_size;

  // ---- workspace layout: peak 120 MB, heavy aliasing (lifetimes verified) ---
  const size_t MB = 1ull << 20;
  char* ws = (char*)d_ws;
  bf16* wqkv = (bf16*)(ws + 0 * MB);      // 6 MB [wq|wk|wv stacked rows]
  bf16* wo = (bf16*)(ws + 6 * MB);        // 2 MB
  bf16* w1 = (bf16*)(ws + 8 * MB);        // 8 MB
  bf16* w2 = (bf16*)(ws + 16 * MB);       // 8 MB
  bf16* Cqkv = (bf16*)(ws + 24 * MB);     // 48 MB [8192][3072]
  bf16* Vt = (bf16*)(ws + 72 * MB);       // 16 MB [b][E][S]
  bf16* scoresB = (bf16*)(ws + 88 * MB);  // 32 MB [88..120)
  bf16* xln = (bf16*)(ws + 88 * MB);      // 16 MB (dead before scores written)
  float* bqkv = (float*)(ws + 104 * MB);  // 12 KB (dead before scores written)
  bf16* ctx = Cqkv;                       // alias (Cqkv dead after transpose)
  bf16* pw = (bf16*)(ws + 40 * MB);       // 32 MB: Wo split-K partials
  bf16* hn = scoresB;                     // alias (scores dead after PV)
  bf16* f1 = (bf16*)(ws + 24 * MB);       // 64 MB [24..88)
  bf16* pp = (bf16*)(ws + 88 * MB);       // 32 MB: FF2 split-K partials
  float* h = out;                         // residual stream lives in d_out

  // ONE prep dispatch: LN1 + all weight converts + bias gathers
  prep_k<<<PREP_CVT + 3, 256, 0, stream>>>(
      src, Wq_w, Wk_w, Wv_w, Wo_w, W1_w, W2_w, Wq_b, Wk_b, Wv_b, g1, b1,
      wqkv, wo, w1, w2, bqkv, xln);

  // QKV fused: [8192][3072] = xln @ wqkv^T + bqkv
  dim3 gQKV(QKV_N / 256, NTOK / 256);
  gemm8p_k<256, bf16, false><<<gQKV, 512, 0, stream>>>(
      xln, E_DIM, wqkv, E_DIM, Cqkv, QKV_N, NTOK, QKV_N, E_DIM,
      bqkv, nullptr, 0, 1.0f, 0, 0, 0);

  // scores[b] = (Q K^T) / 32 -> bf16, z-batched (Q,K strided views of Cqkv)
  dim3 gSc(S_DIM / 256, S_DIM / 256, B_DIM);
  gemm8p_k<256, bf16, false><<<gSc, 512, 0, stream>>>(
      Cqkv, QKV_N, Cqkv + E_DIM, QKV_N, scoresB, S_DIM, S_DIM, S_DIM, E_DIM,
      nullptr, nullptr, 0, 1.0f / 32.0f,
      (size_t)S_DIM * QKV_N, (size_t)S_DIM * QKV_N, (size_t)S_DIM * S_DIM);

  // softmax rows, in-place bf16
  softmax_k<<<B_DIM * S_DIM, 256, 0, stream>>>(scoresB);

  // V transpose per batch (V = cols [2048..3072) of Cqkv)
  transpose_k<<<dim3(E_DIM / 32, S_DIM / 32, B_DIM), 256, 0, stream>>>(
      Cqkv + 2 * E_DIM, QKV_N, (size_t)S_DIM * QKV_N, Vt);

  // ctx[b] = P V, z-batched (writes over Cqkv start; P + Vt still live)
  dim3 gPV(E_DIM / 128, S_DIM / 256, B_DIM);
  gemm8p_k<128, bf16, false><<<gPV, 512, 0, stream>>>(
      scoresB, S_DIM, Vt, S_DIM, ctx, E_DIM, S_DIM, E_DIM, S_DIM,
      nullptr, nullptr, 0, 1.0f,
      (size_t)S_DIM * S_DIM, (size_t)S_DIM * E_DIM, (size_t)S_DIM * E_DIM);

  // Wo split-K=2, ONE dispatch: pw[z] = ctx[:, zK:] @ wo[:, zK:]^T
  dim3 gWo(E_DIM / 256, NTOK / 256, 2);
  gemm8p_k<256, bf16, false><<<gWo, 512, 0, stream>>>(
      ctx, E_DIM, wo, E_DIM, pw, E_DIM, NTOK, E_DIM, E_DIM / 2,
      nullptr, nullptr, 0, 1.0f,
      (size_t)(E_DIM / 2), (size_t)(E_DIM / 2), (size_t)NTOK * E_DIM);

  // LN2 fused with Wo reduce: h = src + pw0 + pw1 + bo; hn = LN(h)
  ln2_fused_k<<<NTOK, 256, 0, stream>>>(
      src, pw, pw + (size_t)NTOK * E_DIM, Wo_b, h, hn, g2, b2);

  // f1 = relu(hn @ W1^T + b1)
  dim3 gF1(FF_DIM / 256, NTOK / 256);
  gemm8p_k<256, bf16, true><<<gF1, 512, 0, stream>>>(
      hn, E_DIM, w1, E_DIM, f1, FF_DIM, NTOK, FF_DIM, E_DIM,
      W1_b, nullptr, 0, 1.0f, 0, 0, 0);

  // FF2 split-K=2, ONE dispatch: pp[z] = f1[:, zK:] @ w2[:, zK:]^T
  dim3 gF2(E_DIM / 256, NTOK / 256, 2);
  gemm8p_k<256, bf16, false><<<gF2, 512, 0, stream>>>(
      f1, FF_DIM, w2, FF_DIM, pp, E_DIM, NTOK, E_DIM, FF_DIM / 2,
      nullptr, nullptr, 0, 1.0f,
      (size_t)(FF_DIM / 2), (size_t)(FF_DIM / 2), (size_t)NTOK * E_DIM);

  // LN3 fused with the split-K reduce: out = LN(h + p0 + p1 + b2)
  ln3_fused_k<<<NTOK, 256, 0, stream>>>(
      h, pp, pp + (size_t)NTOK * E_DIM, W2_b, out, g3, b3);
}

// Round 14
// 363.483 us; speedup vs baseline: 1.1776x; 1.0534x over previous
//
#include <hip/hip_runtime.h>
#include <cstdint>
#include <cmath>

#define E_DIM 1024
#define FF_DIM 4096
#define B_DIM 4
#define S_DIM 2048
#define NTOK (B_DIM * S_DIM)  // 8192
#define QKV_N 3072

typedef __bf16 bf16;
typedef __attribute__((ext_vector_type(8))) __bf16 bf16x8;
typedef __attribute__((ext_vector_type(4))) float f32x4;

// ---- async global->LDS, 16B per lane (HW: dest = wave-uniform base + lane*16)
__device__ __forceinline__ void gload_lds16(const void* g, void* l) {
  __builtin_amdgcn_global_load_lds(
      (const __attribute__((address_space(1))) unsigned int*)g,
      (__attribute__((address_space(3))) unsigned int*)l, 16, 0, 0);
}

__device__ __forceinline__ float waveRedSum(float v) {
#pragma unroll
  for (int o = 32; o > 0; o >>= 1) v += __shfl_xor(v, o, 64);
  return v;
}
__device__ __forceinline__ float waveRedMax(float v) {
#pragma unroll
  for (int o = 32; o > 0; o >>= 1) v = fmaxf(v, __shfl_xor(v, o, 64));
  return v;
}

// ============================================================================
// prep_k: ONE dispatch replacing {LN1, 6x weight cvt, 3x bias memcpy}.
// ============================================================================
#define PREP_LN 8192
#define PREP_CVT (PREP_LN + 12288)
__global__ __launch_bounds__(256) void prep_k(
    const float* __restrict__ src, const float* __restrict__ Wq_w,
    const float* __restrict__ Wk_w, const float* __restrict__ Wv_w,
    const float* __restrict__ Wo_w, const float* __restrict__ W1_w,
    const float* __restrict__ W2_w, const float* __restrict__ Wq_b,
    const float* __restrict__ Wk_b, const float* __restrict__ Wv_b,
    const float* __restrict__ g1, const float* __restrict__ b1,
    bf16* __restrict__ wqkv, bf16* __restrict__ wo, bf16* __restrict__ w1,
    bf16* __restrict__ w2, float* __restrict__ bqkv, bf16* __restrict__ xln) {
  const int blk = blockIdx.x;
  const int tid = threadIdx.x;
  if (blk < PREP_LN) {
    const int row = blk;
    const float4 v = reinterpret_cast<const float4*>(src + (size_t)row * E_DIM)[tid];
    float s = v.x + v.y + v.z + v.w;
    float q = v.x * v.x + v.y * v.y + v.z * v.z + v.w * v.w;
    s = waveRedSum(s);
    q = waveRedSum(q);
    __shared__ float sa[4], sb[4];
    const int lane = tid & 63, wid = tid >> 6;
    if (lane == 0) { sa[wid] = s; sb[wid] = q; }
    __syncthreads();
    s = sa[0] + sa[1] + sa[2] + sa[3];
    q = sb[0] + sb[1] + sb[2] + sb[3];
    const float mean = s * (1.0f / E_DIM);
    const float var = q * (1.0f / E_DIM) - mean * mean;
    const float rstd = rsqrtf(var + 1e-5f);
    const int c = tid * 4;
    bf16* op = xln + (size_t)row * E_DIM + c;
    const float vv[4] = {v.x, v.y, v.z, v.w};
#pragma unroll
    for (int j = 0; j < 4; ++j)
      op[j] = (bf16)((vv[j] - mean) * rstd * g1[c + j] + b1[c + j]);
  } else if (blk < PREP_CVT) {
    int l = blk - PREP_LN;
    const float* in;
    bf16* out;
    if (l < 1024)        { in = Wq_w; out = wqkv;                                }
    else if (l < 2048)   { in = Wk_w; out = wqkv + (size_t)E_DIM * E_DIM;  l -= 1024; }
    else if (l < 3072)   { in = Wv_w; out = wqkv + 2 * (size_t)E_DIM * E_DIM; l -= 2048; }
    else if (l < 4096)   { in = Wo_w; out = wo;   l -= 3072; }
    else if (l < 8192)   { in = W1_w; out = w1;   l -= 4096; }
    else                 { in = W2_w; out = w2;   l -= 8192; }
    const size_t i = (size_t)l * 256 + tid;
    float4 v = reinterpret_cast<const float4*>(in)[i];
    bf16* o = out + i * 4;
    o[0] = (bf16)v.x; o[1] = (bf16)v.y; o[2] = (bf16)v.z; o[3] = (bf16)v.w;
  } else {
    const int bsel = blk - PREP_CVT;
    const float* in = (bsel == 0) ? Wq_b : (bsel == 1) ? Wk_b : Wv_b;
    reinterpret_cast<float4*>(bqkv + bsel * E_DIM)[tid] =
        reinterpret_cast<const float4*>(in)[tid];
  }
}

// ---- LN2 fused with Wo split-K reduce ---------------------------------------
__global__ __launch_bounds__(256) void ln2_fused_k(
    const float* __restrict__ src, const bf16* __restrict__ p0,
    const bf16* __restrict__ p1, const float* __restrict__ bo,
    float* __restrict__ h, bf16* __restrict__ hn,
    const float* __restrict__ g, const float* __restrict__ b) {
  const int row = blockIdx.x;
  const int tid = threadIdx.x;
  const int c = tid * 4;
  const float4 sv = reinterpret_cast<const float4*>(src + (size_t)row * E_DIM)[tid];
  const ushort4 a0 = reinterpret_cast<const ushort4*>(p0 + (size_t)row * E_DIM)[tid];
  const ushort4 a1 = reinterpret_cast<const ushort4*>(p1 + (size_t)row * E_DIM)[tid];
  const float4 bv = reinterpret_cast<const float4*>(bo)[tid];
  auto b2f = [](unsigned short u) {
    union { unsigned int i; float f; } t; t.i = (unsigned int)u << 16; return t.f;
  };
  float x[4];
  x[0] = sv.x + b2f(a0.x) + b2f(a1.x) + bv.x;
  x[1] = sv.y + b2f(a0.y) + b2f(a1.y) + bv.y;
  x[2] = sv.z + b2f(a0.z) + b2f(a1.z) + bv.z;
  x[3] = sv.w + b2f(a0.w) + b2f(a1.w) + bv.w;
  float4 hv = {x[0], x[1], x[2], x[3]};
  reinterpret_cast<float4*>(h + (size_t)row * E_DIM)[tid] = hv;
  float s = x[0] + x[1] + x[2] + x[3];
  float q = x[0] * x[0] + x[1] * x[1] + x[2] * x[2] + x[3] * x[3];
  s = waveRedSum(s);
  q = waveRedSum(q);
  __shared__ float sa[4], sb[4];
  const int lane = tid & 63, wid = tid >> 6;
  if (lane == 0) { sa[wid] = s; sb[wid] = q; }
  __syncthreads();
  s = sa[0] + sa[1] + sa[2] + sa[3];
  q = sb[0] + sb[1] + sb[2] + sb[3];
  const float mean = s * (1.0f / E_DIM);
  const float var = q * (1.0f / E_DIM) - mean * mean;
  const float rstd = rsqrtf(var + 1e-5f);
  bf16* op = hn + (size_t)row * E_DIM + c;
#pragma unroll
  for (int j = 0; j < 4; ++j)
    op[j] = (bf16)((x[j] - mean) * rstd * g[c + j] + b[c + j]);
}

// ---- LN3 fused with FF2 split-K reduce --------------------------------------
__global__ __launch_bounds__(256) void ln3_fused_k(
    const float* __restrict__ h, const bf16* __restrict__ p0,
    const bf16* __restrict__ p1, const float* __restrict__ bias2,
    float* __restrict__ out, const float* __restrict__ g,
    const float* __restrict__ b) {
  const int row = blockIdx.x;
  const int tid = threadIdx.x;
  const int c = tid * 4;
  const float4 hv = reinterpret_cast<const float4*>(h + (size_t)row * E_DIM)[tid];
  const ushort4 a0 = reinterpret_cast<const ushort4*>(p0 + (size_t)row * E_DIM)[tid];
  const ushort4 a1 = reinterpret_cast<const ushort4*>(p1 + (size_t)row * E_DIM)[tid];
  const float4 bv = reinterpret_cast<const float4*>(bias2)[tid];
  auto b2f = [](unsigned short u) {
    union { unsigned int i; float f; } t; t.i = (unsigned int)u << 16; return t.f;
  };
  float x[4];
  x[0] = hv.x + b2f(a0.x) + b2f(a1.x) + bv.x;
  x[1] = hv.y + b2f(a0.y) + b2f(a1.y) + bv.y;
  x[2] = hv.z + b2f(a0.z) + b2f(a1.z) + bv.z;
  x[3] = hv.w + b2f(a0.w) + b2f(a1.w) + bv.w;
  float s = x[0] + x[1] + x[2] + x[3];
  float q = x[0] * x[0] + x[1] * x[1] + x[2] * x[2] + x[3] * x[3];
  s = waveRedSum(s);
  q = waveRedSum(q);
  __shared__ float sa[4], sb[4];
  const int lane = tid & 63, wid = tid >> 6;
  if (lane == 0) { sa[wid] = s; sb[wid] = q; }
  __syncthreads();
  s = sa[0] + sa[1] + sa[2] + sa[3];
  q = sb[0] + sb[1] + sb[2] + sb[3];
  const float mean = s * (1.0f / E_DIM);
  const float var = q * (1.0f / E_DIM) - mean * mean;
  const float rstd = rsqrtf(var + 1e-5f);
  float* op = out + (size_t)row * E_DIM + c;
#pragma unroll
  for (int j = 0; j < 4; ++j)
    op[j] = (x[j] - mean) * rstd * g[c + j] + b[c + j];
}

// ---------------- row softmax over S=2048, in-place bf16 ---------------------
__global__ __launch_bounds__(256) void softmax_k(bf16* __restrict__ scores) {
  const int row = blockIdx.x;
  bf16* rp = scores + (size_t)row * S_DIM;
  const int tid = threadIdx.x;
  const int lane = tid & 63, wid = tid >> 6;
  bf16x8 v8 = *reinterpret_cast<const bf16x8*>(rp + tid * 8);
  float v[8];
#pragma unroll
  for (int j = 0; j < 8; ++j) v[j] = (float)v8[j];
  float mx = v[0];
#pragma unroll
  for (int j = 1; j < 8; ++j) mx = fmaxf(mx, v[j]);
  mx = waveRedMax(mx);
  __shared__ float sm_[4], ss_[4];
  if (lane == 0) sm_[wid] = mx;
  __syncthreads();
  mx = fmaxf(fmaxf(sm_[0], sm_[1]), fmaxf(sm_[2], sm_[3]));
  float e[8];
  float s = 0.f;
#pragma unroll
  for (int j = 0; j < 8; ++j) { e[j] = __expf(v[j] - mx); s += e[j]; }
  s = waveRedSum(s);
  if (lane == 0) ss_[wid] = s;
  __syncthreads();
  s = ss_[0] + ss_[1] + ss_[2] + ss_[3];
  const float inv = 1.0f / s;
  bf16x8 o;
#pragma unroll
  for (int j = 0; j < 8; ++j) o[j] = (bf16)(e[j] * inv);
  *reinterpret_cast<bf16x8*>(rp + tid * 8) = o;
}

// -------- bf16 transpose [S][ld_in] cols -> [E][S] per batch (strided in) ----
__global__ __launch_bounds__(256) void transpose_k(const bf16* __restrict__ in,
                                                   int ld_in, size_t bstride_in,
                                                   bf16* __restrict__ out) {
  __shared__ bf16 t[32][33];
  const int b = blockIdx.z;
  const bf16* ip = in + (size_t)b * bstride_in;
  bf16* op = out + (size_t)b * S_DIM * E_DIM;
  const int e0 = blockIdx.x * 32, s0 = blockIdx.y * 32;
  const int tx = threadIdx.x & 31, ty = threadIdx.x >> 5;  // 32 x 8
#pragma unroll
  for (int r = 0; r < 32; r += 8)
    t[ty + r][tx] = ip[(size_t)(s0 + ty + r) * ld_in + e0 + tx];
  __syncthreads();
#pragma unroll
  for (int r = 0; r < 32; r += 8)
    op[(size_t)(e0 + ty + r) * S_DIM + s0 + tx] = t[tx][ty + r];
}

// ============================================================================
// 256xBN 8-wave GEMM, BK=64, counted vmcnt, MINIMAL-BARRIER schedule (r14).
// Barriers ONLY after each vmcnt wait (the points where cross-wave gload->LDS
// visibility must be published): BN=256 at p1-end + p3-end; BN=128 at p1-end.
// Waves free-run between barriers -> a SIMD's 2 waves overlap ds_read/MFMA
// phases (m114 mechanism intra-block). Wait ledger identical to r11/r13
// (re-audited with desynced waves: WAR on buffer reuse and RAW on staged
// chunks are all covered by the two retained barrier points).
// C = scale*(A @ Bt^T) + bias (+resid) (+relu).  A: MxK (lda), Bt: NxK (ldb).
// Swizzle (T2): rows are 128 B; 16B-group g ^= (row&7); inverse applied on
// global source (gload_lds dest stays linear), same XOR on ds_read.
// ============================================================================
template <int BN, typename OutT, bool RELU>
__global__ __launch_bounds__(512) void gemm8p_k(
    const bf16* __restrict__ A0, int lda, const bf16* __restrict__ Bt0, int ldb,
    OutT* __restrict__ C0, int ldc, int M, int N, int K,
    const float* __restrict__ bias, const float* __restrict__ resid, int ldr,
    float scale, size_t sAz, size_t sBz, size_t sCz) {
  constexpr int BM = 256;
  constexpr int NCH_B = BN / 64;            // B chunks: 4 or 2
  constexpr int NCH = 4 + NCH_B;            // total chunks: 8 or 6
  constexpr int DEPTH = (BN == 256) ? 2 : 3;
  constexpr int DBUF = (BM + BN) * 128;     // bytes per tile buffer
  __shared__ __align__(16) char smem[DEPTH * DBUF];

  const int tid = threadIdx.x;
  const int lane = tid & 63;
  const int wid = tid >> 6;   // 0..7

  const bf16* A = A0 + (size_t)blockIdx.z * sAz;
  const bf16* Bt = Bt0 + (size_t)blockIdx.z * sBz;
  OutT* C = C0 + (size_t)blockIdx.z * sCz;

  // T1: bijective XCD-aware remap (m204)
  const int gx = gridDim.x;
  const int nwg = gx * gridDim.y;
  int wg = blockIdx.y * gx + blockIdx.x;
  {
    const int q = nwg >> 3, r8_ = nwg & 7;
    const int xcd = wg & 7, lin = wg >> 3;
    wg = (xcd < r8_ ? xcd * (q + 1) : r8_ * (q + 1) + (xcd - r8_) * q) + lin;
  }
  const int m0 = (wg / gx) * 256;
  const int n0 = (wg % gx) * BN;

  // stage chunk c of tile t into buffer t%DEPTH. Linear LDS dest; source
  // inverse-swizzled.
  auto stage_chunk = [&](int t, int c) {
    char* base = smem + (t % DEPTH) * DBUF;
    const int r8 = tid >> 3;  // 0..63 row within chunk
    const int gg = tid & 7;   // 16B group
    if (c < NCH_B) {
      const int row = c * 64 + r8;
      const int g = gg ^ (row & 7);
      gload_lds16(Bt + (size_t)(n0 + row) * ldb + t * 64 + g * 8,
                  base + BM * 128 + c * 8192 + wid * 1024);
    } else {
      const int i = c - NCH_B;
      const int ca = ((i & 1) << 1) | (i >> 1);  // order A0,A2,A1,A3
      const int row = ca * 64 + r8;
      const int g = gg ^ (row & 7);
      gload_lds16(A + (size_t)(m0 + row) * lda + t * 64 + g * 8,
                  base + ca * 8192 + wid * 1024);
    }
  };

  f32x4 accQ[2][4][2][2] = {};  // BN=256: [mh][fm][nh][fn]
  f32x4 accH[4][4] = {};        // BN=128: [fm][fn]

  const int NT = K >> 6;
  // prologue
  if constexpr (BN == 256) {
#pragma unroll
    for (int c = 0; c < NCH; ++c) stage_chunk(0, c);
    asm volatile("s_waitcnt vmcnt(2)" ::: "memory");
  } else {
#pragma unroll
    for (int c = 0; c < NCH; ++c) stage_chunk(0, c);
#pragma unroll
    for (int c = 0; c < NCH; ++c) stage_chunk(1, c);
    asm volatile("s_waitcnt vmcnt(6)" ::: "memory");  // tile0 landed
  }
  __builtin_amdgcn_s_barrier();

  for (int t = 0; t < NT; ++t) {
    const char* lA = smem + (t % DEPTH) * DBUF;
    const char* lB = lA + BM * 128;
    if constexpr (BN == 256) {
      const int wr = wid >> 2;  // 0..1 (M)
      const int wc = wid & 3;   // 0..3 (N)
      bf16x8 af[4][2];
      bf16x8 bfv[2][2][2];
#pragma unroll
      for (int p = 0; p < 4; ++p) {
        const int mh = p >> 1, nh = p & 1;
        if (p == 0 || p == 2) {
#pragma unroll
          for (int fm = 0; fm < 4; ++fm) {
            const int row = wr * 128 + mh * 64 + fm * 16 + (lane & 15);
#pragma unroll
            for (int ks = 0; ks < 2; ++ks) {
              const int g = ((ks << 2) | (lane >> 4)) ^ (row & 7);
              af[fm][ks] = *reinterpret_cast<const bf16x8*>(lA + row * 128 + g * 16);
            }
          }
        }
        if (p < 2) {
#pragma unroll
          for (int fn = 0; fn < 2; ++fn) {
            const int row = wc * 64 + p * 32 + fn * 16 + (lane & 15);
#pragma unroll
            for (int ks = 0; ks < 2; ++ks) {
              const int g = ((ks << 2) | (lane >> 4)) ^ (row & 7);
              bfv[p][fn][ks] =
                  *reinterpret_cast<const bf16x8*>(lB + row * 128 + g * 16);
            }
          }
        }
        if (t + 1 < NT) {
#pragma unroll
          for (int c = 0; c < 2; ++c) stage_chunk(t + 1, p * 2 + c);
        }
        __builtin_amdgcn_s_setprio(1);
#pragma unroll
        for (int fm = 0; fm < 4; ++fm)
#pragma unroll
          for (int fn = 0; fn < 2; ++fn) {
            accQ[mh][fm][nh][fn] = __builtin_amdgcn_mfma_f32_16x16x32_bf16(
                af[fm][0], bfv[nh][fn][0], accQ[mh][fm][nh][fn], 0, 0, 0);
            accQ[mh][fm][nh][fn] = __builtin_amdgcn_mfma_f32_16x16x32_bf16(
                af[fm][1], bfv[nh][fn][1], accQ[mh][fm][nh][fn], 0, 0, 0);
          }
        __builtin_amdgcn_s_setprio(0);
        if (p == 1) {
          // drains current tile's A1,A3 (issued prev-tile p3) before p2 reads
          if (t + 1 < NT) asm volatile("s_waitcnt vmcnt(4)" ::: "memory");
          else            asm volatile("s_waitcnt vmcnt(0)" ::: "memory");
          __builtin_amdgcn_s_barrier();  // publish cross-wave LDS visibility
        }
        if (p == 3) {
          // boundary: drains next tile's B0..B3,A0,A2 (t+1's p3 pair stays)
          asm volatile("s_waitcnt vmcnt(2)" ::: "memory");
          __builtin_amdgcn_s_barrier();
        }
      }
    } else {
      // BN=128, 4Mx2N waves, wave tile 64x64, phases = K-halves (ks)
      const int wr = wid >> 1;  // 0..3 (M)
      const int wc = wid & 1;   // 0..1 (N)
#pragma unroll
      for (int p = 0; p < 2; ++p) {
        bf16x8 af[4], bf[4];
#pragma unroll
        for (int fm = 0; fm < 4; ++fm) {
          const int row = wr * 64 + fm * 16 + (lane & 15);
          const int g = ((p << 2) | (lane >> 4)) ^ (row & 7);
          af[fm] = *reinterpret_cast<const bf16x8*>(lA + row * 128 + g * 16);
        }
#pragma unroll
        for (int fn = 0; fn < 4; ++fn) {
          const int row = wc * 64 + fn * 16 + (lane & 15);
          const int g = ((p << 2) | (lane >> 4)) ^ (row & 7);
          bf[fn] = *reinterpret_cast<const bf16x8*>(lB + row * 128 + g * 16);
        }
        if (t + 2 < NT) {
#pragma unroll
          for (int c = 0; c < 3; ++c) stage_chunk(t + 2, p * 3 + c);
        }
        __builtin_amdgcn_s_setprio(1);
#pragma unroll
        for (int fm = 0; fm < 4; ++fm)
#pragma unroll
          for (int fn = 0; fn < 4; ++fn)
            accH[fm][fn] = __builtin_amdgcn_mfma_f32_16x16x32_bf16(
                af[fm], bf[fn], accH[fm][fn], 0, 0, 0);
        __builtin_amdgcn_s_setprio(0);
        if (p == 1) {
          // boundary: tile t+1 must be landed; t+2's 6 stay in flight
          if (t + 2 < NT) asm volatile("s_waitcnt vmcnt(6)" ::: "memory");
          else            asm volatile("s_waitcnt vmcnt(0)" ::: "memory");
          __builtin_amdgcn_s_barrier();
        }
      }
    }
  }

  // --------------------------- epilogue -------------------------------------
  if constexpr (BN == 256) {
    const int wr = wid >> 2, wc = wid & 3;
#pragma unroll
    for (int mh = 0; mh < 2; ++mh)
#pragma unroll
      for (int nh = 0; nh < 2; ++nh)
#pragma unroll
        for (int fn = 0; fn < 2; ++fn) {
          const int col = n0 + wc * 64 + nh * 32 + fn * 16 + (lane & 15);
          const float bv = bias ? bias[col] : 0.0f;
#pragma unroll
          for (int fm = 0; fm < 4; ++fm)
#pragma unroll
            for (int i = 0; i < 4; ++i) {
              const int row = m0 + wr * 128 + mh * 64 + fm * 16 + (lane >> 4) * 4 + i;
              float v = accQ[mh][fm][nh][fn][i] * scale + bv;
              if (resid) v += resid[(size_t)row * ldr + col];
              if (RELU) v = fmaxf(v, 0.0f);
              C[(size_t)row * ldc + col] = (OutT)v;
            }
        }
  } else {
    const int wr = wid >> 1, wc = wid & 1;
#pragma unroll
    for (int fn = 0; fn < 4; ++fn) {
      const int col = n0 + wc * 64 + fn * 16 + (lane & 15);
      const float bv = bias ? bias[col] : 0.0f;
#pragma unroll
      for (int fm = 0; fm < 4; ++fm)
#pragma unroll
        for (int i = 0; i < 4; ++i) {
          const int row = m0 + wr * 64 + fm * 16 + (lane >> 4) * 4 + i;
          float v = accH[fm][fn][i] * scale + bv;
          if (resid) v += resid[(size_t)row * ldr + col];
          if (RELU) v = fmaxf(v, 0.0f);
          C[(size_t)row * ldc + col] = (OutT)v;
        }
    }
  }
}

// =============================================================================
extern "C" void kernel_launch(void* const* d_in, const int* in_sizes, int n_in,
                              void* d_out, int out_size, void* d_ws,
                              size_t ws_size, hipStream_t stream) {
  const float* src = (const float*)d_in[0];
  const float* Wq_w = (const float*)d_in[1];
  const float* Wq_b = (const float*)d_in[2];
  const float* Wk_w = (const float*)d_in[3];
  const float* Wk_b = (const float*)d_in[4];
  const float* Wv_w = (const float*)d_in[5];
  const float* Wv_b = (const float*)d_in[6];
  const float* Wo_w = (const float*)d_in[7];
  const float* Wo_b = (const float*)d_in[8];
  const float* W1_w = (const float*)d_in[9];
  const float* W1_b = (const float*)d_in[10];
  const float* W2_w = (const float*)d_in[11];
  const float* W2_b = (const float*)d_in[12];
  const float* g1 = (const float*)d_in[13];
  const float* b1 = (const float*)d_in[14];
  const float* g2 = (const float*)d_in[15];
  const float* b2 = (const float*)d_in[16];
  const float* g3 = (const float*)d_in[17];
  const float* b3 = (const float*)d_in[18];
  float* out = (float*)d_out;
  (void)ws_size; (void)in_sizes; (void)n_in; (void)out_size;

  // ---- workspace layout: peak 120 MB, heavy aliasing (lifetimes verified) ---
  const size_t MB = 1ull << 20;
  char* ws = (char*)d_ws;
  bf16* wqkv = (bf16*)(ws + 0 * MB);      // 6 MB [wq|wk|wv stacked rows]
  bf16* wo = (bf16*)(ws + 6 * MB);        // 2 MB
  bf16* w1 = (bf16*)(ws + 8 * MB);        // 8 MB
  bf16* w2 = (bf16*)(ws + 16 * MB);       // 8 MB
  bf16* Cqkv = (bf16*)(ws + 24 * MB);     // 48 MB [8192][3072]
  bf16* Vt = (bf16*)(ws + 72 * MB);       // 16 MB [b][E][S]
  bf16* scoresB = (bf16*)(ws + 88 * MB);  // 32 MB [88..120)
  bf16* xln = (bf16*)(ws + 88 * MB);      // 16 MB (dead before scores written)
  float* bqkv = (float*)(ws + 104 * MB);  // 12 KB (dead before scores written)
  bf16* ctx = Cqkv;                       // alias (Cqkv dead after transpose)
  bf16* pw = (bf16*)(ws + 40 * MB);       // 32 MB: Wo split-K partials
  bf16* hn = scoresB;                     // alias (scores dead after PV)
  bf16* f1 = (bf16*)(ws + 24 * MB);       // 64 MB [24..88)
  bf16* pp = (bf16*)(ws + 88 * MB);       // 32 MB: FF2 split-K partials
  float* h = out;                         // residual stream lives in d_out

  // ONE prep dispatch: LN1 + all weight converts + bias gathers
  prep_k<<<PREP_CVT + 3, 256, 0, stream>>>(
      src, Wq_w, Wk_w, Wv_w, Wo_w, W1_w, W2_w, Wq_b, Wk_b, Wv_b, g1, b1,
      wqkv, wo, w1, w2, bqkv, xln);

  // QKV fused: [8192][3072] = xln @ wqkv^T + bqkv
  dim3 gQKV(QKV_N / 256, NTOK / 256);
  gemm8p_k<256, bf16, false><<<gQKV, 512, 0, stream>>>(
      xln, E_DIM, wqkv, E_DIM, Cqkv, QKV_N, NTOK, QKV_N, E_DIM,
      bqkv, nullptr, 0, 1.0f, 0, 0, 0);

  // scores[b] = (Q K^T) / 32 -> bf16, z-batched (Q,K strided views of Cqkv)
  dim3 gSc(S_DIM / 256, S_DIM / 256, B_DIM);
  gemm8p_k<256, bf16, false><<<gSc, 512, 0, stream>>>(
      Cqkv, QKV_N, Cqkv + E_DIM, QKV_N, scoresB, S_DIM, S_DIM, S_DIM, E_DIM,
      nullptr, nullptr, 0, 1.0f / 32.0f,
      (size_t)S_DIM * QKV_N, (size_t)S_DIM * QKV_N, (size_t)S_DIM * S_DIM);

  // softmax rows, in-place bf16
  softmax_k<<<B_DIM * S_DIM, 256, 0, stream>>>(scoresB);

  // V transpose per batch (V = cols [2048..3072) of Cqkv)
  transpose_k<<<dim3(E_DIM / 32, S_DIM / 32, B_DIM), 256, 0, stream>>>(
      Cqkv + 2 * E_DIM, QKV_N, (size_t)S_DIM * QKV_N, Vt);

  // ctx[b] = P V, z-batched (writes over Cqkv start; P + Vt still live)
  dim3 gPV(E_DIM / 128, S_DIM / 256, B_DIM);
  gemm8p_k<128, bf16, false><<<gPV, 512, 0, stream>>>(
      scoresB, S_DIM, Vt, S_DIM, ctx, E_DIM, S_DIM, E_DIM, S_DIM,
      nullptr, nullptr, 0, 1.0f,
      (size_t)S_DIM * S_DIM, (size_t)S_DIM * E_DIM, (size_t)S_DIM * E_DIM);

  // Wo split-K=2, ONE dispatch: pw[z] = ctx[:, zK:] @ wo[:, zK:]^T
  dim3 gWo(E_DIM / 256, NTOK / 256, 2);
  gemm8p_k<256, bf16, false><<<gWo, 512, 0, stream>>>(
      ctx, E_DIM, wo, E_DIM, pw, E_DIM, NTOK, E_DIM, E_DIM / 2,
      nullptr, nullptr, 0, 1.0f,
      (size_t)(E_DIM / 2), (size_t)(E_DIM / 2), (size_t)NTOK * E_DIM);

  // LN2 fused with Wo reduce: h = src + pw0 + pw1 + bo; hn = LN(h)
  ln2_fused_k<<<NTOK, 256, 0, stream>>>(
      src, pw, pw + (size_t)NTOK * E_DIM, Wo_b, h, hn, g2, b2);

  // f1 = relu(hn @ W1^T + b1)
  dim3 gF1(FF_DIM / 256, NTOK / 256);
  gemm8p_k<256, bf16, true><<<gF1, 512, 0, stream>>>(
      hn, E_DIM, w1, E_DIM, f1, FF_DIM, NTOK, FF_DIM, E_DIM,
      W1_b, nullptr, 0, 1.0f, 0, 0, 0);

  // FF2 split-K=2, ONE dispatch: pp[z] = f1[:, zK:] @ w2[:, zK:]^T
  dim3 gF2(E_DIM / 256, NTOK / 256, 2);
  gemm8p_k<256, bf16, false><<<gF2, 512, 0, stream>>>(
      f1, FF_DIM, w2, FF_DIM, pp, E_DIM, NTOK, E_DIM, FF_DIM / 2,
      nullptr, nullptr, 0, 1.0f,
      (size_t)(FF_DIM / 2), (size_t)(FF_DIM / 2), (size_t)NTOK * E_DIM);

  // LN3 fused with the split-K reduce: out = LN(h + p0 + p1 + b2)
  ln3_fused_k<<<NTOK, 256, 0, stream>>>(
      h, pp, pp + (size_t)NTOK * E_DIM, W2_b, out, g3, b3);
}